// Round 1
// baseline (255.721 us; speedup 1.0000x reference)
//
#include <hip/hip_runtime.h>
#include <hip/hip_bf16.h>
#include <math.h>
#include <stdint.h>

typedef __attribute__((ext_vector_type(8))) short short8;
typedef __attribute__((ext_vector_type(4))) float f32x4;

__device__ inline short f2bf(float x) {
  union { float f; uint32_t u; } c; c.f = x;
  uint32_t r = (c.u + 0x7FFFu + ((c.u >> 16) & 1u)) >> 16;
  return (short)(uint16_t)r;
}
__device__ inline float bf2f(short s) {
  union { uint32_t u; float f; } c; c.u = ((uint32_t)(uint16_t)s) << 16;
  return c.f;
}

// ---------------- prep: f32 -> bf16 (8 elems/thread) ----------------
__global__ void f32_to_bf16_kernel(const float* __restrict__ in,
                                   short* __restrict__ out, int n8) {
  int i = blockIdx.x * blockDim.x + threadIdx.x;
  if (i >= n8) return;
  const float4* p = (const float4*)(in + (size_t)i * 8);
  float4 a = p[0], b = p[1];
  short8 o;
  o[0] = f2bf(a.x); o[1] = f2bf(a.y); o[2] = f2bf(a.z); o[3] = f2bf(a.w);
  o[4] = f2bf(b.x); o[5] = f2bf(b.y); o[6] = f2bf(b.z); o[7] = f2bf(b.w);
  *(short8*)(out + (size_t)i * 8) = o;
}

// ---------------- prep: V[4096,1024] f32 -> Vt[1024,4096] bf16 ----------------
__global__ void transpose_bf16_kernel(const float* __restrict__ V,
                                      short* __restrict__ Vt,
                                      int rows /*4096*/, int cols /*1024*/) {
  __shared__ float tile[64][65];
  int n0 = blockIdx.x * 64;  // row block in V (n dim)
  int d0 = blockIdx.y * 64;  // col block in V (d dim)
  int t = threadIdx.x;
#pragma unroll
  for (int r = 0; r < 16; ++r) {
    int idx = t + 256 * r;
    int rr = idx >> 6, cc = idx & 63;
    tile[rr][cc] = V[(size_t)(n0 + rr) * cols + d0 + cc];
  }
  __syncthreads();
#pragma unroll
  for (int r = 0; r < 16; ++r) {
    int idx = t + 256 * r;
    int dd = idx >> 6, nn = idx & 63;
    Vt[(size_t)(d0 + dd) * rows + n0 + nn] = f2bf(tile[nn][dd]);
  }
}

// ---------------- GEMM: C[M,N] = A[M,K] x B[N,K]^T  (bf16 in, f32 acc) ----------------
// 128x128 tile, BK=64, 4 waves (2x2), 16x16x32 bf16 MFMA, 4x4 frags/wave.
// SCORE_MODE: write C as bf16 AND accumulate per-row sum-of-squares into rowss.
// else:       write C as f32.
template <bool SCORE_MODE>
__global__ __launch_bounds__(256) void gemm_bt_kernel(
    const short* __restrict__ A, const short* __restrict__ B,
    void* __restrict__ Cout, float* __restrict__ rowss,
    int M, int N, int K) {
  __shared__ short sA[128 * 64];
  __shared__ short sB[128 * 64];
  const int t = threadIdx.x;
  const int lane = t & 63;
  const int w = t >> 6;
  const int wr = w >> 1, wc = w & 1;
  const int idx = lane & 15, g = lane >> 4;
  const int row0 = blockIdx.y * 128;
  const int col0 = blockIdx.x * 128;

  f32x4 acc[4][4] = {};

  for (int kt = 0; kt < K; kt += 64) {
    // Stage A/B tiles (each 128x64 bf16 = 16KB = 1024 chunks of 16B).
    // Wave-uniform LDS base + lane*16 (global_load_lds semantics).
#pragma unroll
    for (int i = 0; i < 4; ++i) {
      const int c0 = w * 64 + i * 256;  // wave-uniform chunk base
      const int c = c0 + lane;
      const int row = c >> 3, cc = c & 7;
      const short* gA = A + (size_t)(row0 + row) * K + kt + cc * 8;
      const short* gB = B + (size_t)(col0 + row) * K + kt + cc * 8;
      __builtin_amdgcn_global_load_lds(
          (const __attribute__((address_space(1))) void*)gA,
          (__attribute__((address_space(3))) void*)&sA[c0 * 8], 16, 0, 0);
      __builtin_amdgcn_global_load_lds(
          (const __attribute__((address_space(1))) void*)gB,
          (__attribute__((address_space(3))) void*)&sB[c0 * 8], 16, 0, 0);
    }
    __syncthreads();  // drains vmcnt(0) before reads

#pragma unroll
    for (int ks = 0; ks < 64; ks += 32) {
      short8 af[4], bfr[4];
#pragma unroll
      for (int m = 0; m < 4; ++m)
        af[m] = *(const short8*)&sA[(wr * 64 + m * 16 + idx) * 64 + ks + g * 8];
#pragma unroll
      for (int n = 0; n < 4; ++n)
        bfr[n] = *(const short8*)&sB[(wc * 64 + n * 16 + idx) * 64 + ks + g * 8];
#pragma unroll
      for (int m = 0; m < 4; ++m)
#pragma unroll
        for (int n = 0; n < 4; ++n)
          acc[m][n] = __builtin_amdgcn_mfma_f32_16x16x32_bf16(
              af[m], bfr[n], acc[m][n], 0, 0, 0);
    }
    __syncthreads();  // before next tile overwrite
  }

  // Epilogue. C/D layout: col = lane&15, row = 4*(lane>>4) + j.
  if (SCORE_MODE) {
    short* S = (short*)Cout;
#pragma unroll
    for (int m = 0; m < 4; ++m) {
#pragma unroll
      for (int j = 0; j < 4; ++j) {
        const int row = row0 + wr * 64 + m * 16 + g * 4 + j;
        float ss = 0.f;
#pragma unroll
        for (int n = 0; n < 4; ++n) {
          float v = acc[m][n][j];
          ss += v * v;
          S[(size_t)row * N + col0 + wc * 64 + n * 16 + idx] = f2bf(v);
        }
        // reduce across the 16 lanes sharing this row
        ss += __shfl_xor(ss, 1);
        ss += __shfl_xor(ss, 2);
        ss += __shfl_xor(ss, 4);
        ss += __shfl_xor(ss, 8);
        if (idx == 0) atomicAdd(&rowss[row], ss);
      }
    }
  } else {
    float* C = (float*)Cout;
#pragma unroll
    for (int m = 0; m < 4; ++m)
#pragma unroll
      for (int j = 0; j < 4; ++j) {
        const int row = row0 + wr * 64 + m * 16 + g * 4 + j;
#pragma unroll
        for (int n = 0; n < 4; ++n)
          C[(size_t)row * N + col0 + wc * 64 + n * 16 + idx] = acc[m][n][j];
      }
  }
}

// ---------------- normalize + exact GELU, in place on bf16 scores ----------------
__global__ void norm_gelu_kernel(short* __restrict__ S,
                                 const float* __restrict__ rowss, int total8) {
  int i = blockIdx.x * blockDim.x + threadIdx.x;
  if (i >= total8) return;
  size_t base = (size_t)i * 8;
  int row = (int)(base >> 12);  // / 4096
  float scale = 64.0f * rsqrtf(rowss[row]);  // sqrt(N)/l2
  short8 v = *(short8*)(S + base);
  short8 o;
#pragma unroll
  for (int k = 0; k < 8; ++k) {
    float x = bf2f(v[k]) * scale;
    float gl = 0.5f * x * (1.0f + erff(x * 0.70710678118654752f));
    o[k] = f2bf(gl);
  }
  *(short8*)(S + base) = o;
}

extern "C" void kernel_launch(void* const* d_in, const int* in_sizes, int n_in,
                              void* d_out, int out_size, void* d_ws,
                              size_t ws_size, hipStream_t stream) {
  const float* X = (const float*)d_in[0];   // [8192,1024]
  const float* Kp = (const float*)d_in[1];  // [4096,1024]
  const float* Vp = (const float*)d_in[2];  // [4096,1024]
  float* out = (float*)d_out;               // [8192,1024] f32

  const int M = 8192, D1 = 1024, Nn = 4096, D2 = 1024;

  char* ws = (char*)d_ws;
  short* Xb = (short*)ws; ws += (size_t)M * D1 * 2;   // 16 MiB
  short* Kb = (short*)ws; ws += (size_t)Nn * D1 * 2;  // 8 MiB
  short* Vt = (short*)ws; ws += (size_t)D2 * Nn * 2;  // 8 MiB
  short* S  = (short*)ws; ws += (size_t)M * Nn * 2;   // 64 MiB
  float* rowss = (float*)ws;                          // 32 KiB
  (void)ws_size;

  hipMemsetAsync(rowss, 0, M * sizeof(float), stream);
  f32_to_bf16_kernel<<<(M * D1 / 8 + 255) / 256, 256, 0, stream>>>(X, Xb, M * D1 / 8);
  f32_to_bf16_kernel<<<(Nn * D1 / 8 + 255) / 256, 256, 0, stream>>>(Kp, Kb, Nn * D1 / 8);
  transpose_bf16_kernel<<<dim3(Nn / 64, D2 / 64), 256, 0, stream>>>(Vp, Vt, Nn, D2);
  // scores = Xb @ Kb^T, bf16 out + row sum-of-squares
  gemm_bt_kernel<true><<<dim3(Nn / 128, M / 128), 256, 0, stream>>>(
      Xb, Kb, S, rowss, M, Nn, D1);
  norm_gelu_kernel<<<(M * Nn / 8 + 255) / 256, 256, 0, stream>>>(S, rowss, M * Nn / 8);
  // out = W @ Vt^T
  gemm_bt_kernel<false><<<dim3(D2 / 128, M / 128), 256, 0, stream>>>(
      S, Vt, out, nullptr, M, D2, Nn);
}

// Round 2
// 217.553 us; speedup vs baseline: 1.1754x; 1.1754x over previous
//
#include <hip/hip_runtime.h>
#include <hip/hip_bf16.h>
#include <math.h>
#include <stdint.h>

typedef __attribute__((ext_vector_type(8))) short short8;
typedef __attribute__((ext_vector_type(4))) float f32x4;

constexpr int BK = 32;  // K-depth per LDS tile

__device__ inline short f2bf(float x) {
  union { float f; uint32_t u; } c; c.f = x;
  uint32_t r = (c.u + 0x7FFFu + ((c.u >> 16) & 1u)) >> 16;
  return (short)(uint16_t)r;
}
__device__ inline float bf2f(short s) {
  union { uint32_t u; float f; } c; c.u = ((uint32_t)(uint16_t)s) << 16;
  return c.f;
}

// ---------------- prep: f32 -> bf16 (8 elems/thread) ----------------
__global__ void f32_to_bf16_kernel(const float* __restrict__ in,
                                   short* __restrict__ out, int n8) {
  int i = blockIdx.x * blockDim.x + threadIdx.x;
  if (i >= n8) return;
  const float4* p = (const float4*)(in + (size_t)i * 8);
  float4 a = p[0], b = p[1];
  short8 o;
  o[0] = f2bf(a.x); o[1] = f2bf(a.y); o[2] = f2bf(a.z); o[3] = f2bf(a.w);
  o[4] = f2bf(b.x); o[5] = f2bf(b.y); o[6] = f2bf(b.z); o[7] = f2bf(b.w);
  *(short8*)(out + (size_t)i * 8) = o;
}

// ---------------- prep: V[4096,1024] f32 -> Vt[1024,4096] bf16 ----------------
__global__ void transpose_bf16_kernel(const float* __restrict__ V,
                                      short* __restrict__ Vt,
                                      int rows /*4096*/, int cols /*1024*/) {
  __shared__ float tile[64][65];
  int n0 = blockIdx.x * 64;
  int d0 = blockIdx.y * 64;
  int t = threadIdx.x;
#pragma unroll
  for (int r = 0; r < 16; ++r) {
    int idx = t + 256 * r;
    int rr = idx >> 6, cc = idx & 63;
    tile[rr][cc] = V[(size_t)(n0 + rr) * cols + d0 + cc];
  }
  __syncthreads();
#pragma unroll
  for (int r = 0; r < 16; ++r) {
    int idx = t + 256 * r;
    int dd = idx >> 6, nn = idx & 63;
    Vt[(size_t)(d0 + dd) * rows + n0 + nn] = f2bf(tile[nn][dd]);
  }
}

// ---------------- pipelined GEMM: C[M,N] = A[M,K] x B[N,K]^T ----------------
// BM=256 rows, BN cols, BK=32, 8 waves (WM x WN), 3-slot LDS ring,
// counted vmcnt (never 0 in steady state), XOR-swizzled LDS, setprio MFMA.
template <int BN, int WM, int WN, bool SCORE>
__global__ __launch_bounds__(512, 2) void gemm_pipe(
    const short* __restrict__ A, const short* __restrict__ Bm,
    void* __restrict__ Cout, float* __restrict__ rowss,
    const int M, const int N, const int K) {
  constexpr int BM = 256;
  constexpr int MF = BM / WM / 16;       // m-frags per wave
  constexpr int NF = BN / WN / 16;       // n-frags per wave
  constexpr int MH = (MF > 4) ? 2 : 1;   // m-phases per K-tile
  constexpr int MPH = MF / MH;
  constexpr int ASLOT = BM * BK * 2;     // 16 KiB
  constexpr int BSLOT = BN * BK * 2;     // 16 or 8 KiB
  constexpr int SLOT = ASLOT + BSLOT;
  constexpr int A_ROUNDS = ASLOT / 8192; // 2
  constexpr int B_ROUNDS = BSLOT / 8192; // 2 or 1
  constexpr int LOADS = A_ROUNDS + B_ROUNDS;

  __shared__ char lds[3 * SLOT];

  const int t = threadIdx.x;
  const int lane = t & 63;
  const int w = t >> 6;
  const int wm = w / WN;
  const int wn = w % WN;
  const int idx = lane & 15;
  const int g = lane >> 4;

  // XCD-aware bijective block swizzle (grid % 8 == 0 by construction)
  const int nwg = gridDim.x;
  const int bid = blockIdx.x;
  const int id2 = (bid & 7) * (nwg >> 3) + (bid >> 3);
  const int ntn = N / BN;
  const int row0 = (id2 / ntn) * BM;
  const int col0 = (id2 % ntn) * BN;

  // staging decode: linear LDS dest p = t*16 holds logical q = swz(p)
  const int pp = t * 16;
  const int qq = pp ^ (((pp >> 7) & 7) << 4);
  const int rowS = qq >> 6;              // 0..127 within a 128-row round
  const int kkS = ((qq >> 4) & 3) << 3;  // k element offset (0,8,16,24)

  // swizzled per-lane read base: logical byte = row*64 + g*16, row = idx
  int qr = idx * 64 + g * 16;
  qr ^= ((qr >> 7) & 7) << 4;

  const int NT = K / BK;

  auto STAGE = [&](int TT) {
    const int s = TT - (TT / 3) * 3;
    const int kt = TT * BK;
    char* dstA = &lds[s * SLOT + w * 1024];
#pragma unroll
    for (int r = 0; r < A_ROUNDS; ++r) {
      const short* src = A + (size_t)(row0 + r * 128 + rowS) * K + kt + kkS;
      __builtin_amdgcn_global_load_lds(
          (const __attribute__((address_space(1))) void*)src,
          (__attribute__((address_space(3))) void*)(dstA + r * 8192), 16, 0, 0);
    }
    char* dstB = &lds[s * SLOT + ASLOT + w * 1024];
#pragma unroll
    for (int r = 0; r < B_ROUNDS; ++r) {
      const short* src = Bm + (size_t)(col0 + r * 128 + rowS) * K + kt + kkS;
      __builtin_amdgcn_global_load_lds(
          (const __attribute__((address_space(1))) void*)src,
          (__attribute__((address_space(3))) void*)(dstB + r * 8192), 16, 0, 0);
    }
  };

  f32x4 acc[MF][NF] = {};

  // prologue: stage tiles 0,1; certify tile 0
  STAGE(0);
  STAGE(1);
  asm volatile("s_waitcnt vmcnt(%0)" ::"n"(LOADS) : "memory");
  __builtin_amdgcn_s_barrier();
  __builtin_amdgcn_sched_barrier(0);

  for (int T = 0; T < NT; ++T) {
    const int cur = T - (T / 3) * 3;
    const char* aB = &lds[cur * SLOT] + wm * (BM / WM) * 64;
    const char* bB = &lds[cur * SLOT + ASLOT] + wn * (BN / WN) * 64;

    if (T + 2 < NT) STAGE(T + 2);  // issue prefetch, 2 tiles ahead

    short8 bfr[NF];
#pragma unroll
    for (int nf = 0; nf < NF; ++nf)
      bfr[nf] = *(const short8*)(bB + nf * 1024 + qr);

#pragma unroll
    for (int mh = 0; mh < MH; ++mh) {
      short8 af[MPH];
#pragma unroll
      for (int m = 0; m < MPH; ++m)
        af[m] = *(const short8*)(aB + (mh * MPH + m) * 1024 + qr);
      __builtin_amdgcn_s_barrier();
      asm volatile("s_waitcnt lgkmcnt(0)" ::: "memory");
      __builtin_amdgcn_sched_barrier(0);
      __builtin_amdgcn_s_setprio(1);
#pragma unroll
      for (int m = 0; m < MPH; ++m)
#pragma unroll
        for (int nf = 0; nf < NF; ++nf)
          acc[mh * MPH + m][nf] = __builtin_amdgcn_mfma_f32_16x16x32_bf16(
              af[m], bfr[nf], acc[mh * MPH + m][nf], 0, 0, 0);
      __builtin_amdgcn_s_setprio(0);
      __builtin_amdgcn_sched_barrier(0);
    }

    // certify tile T+1 (counted), or drain at the tail
    if (T + 2 < NT) {
      asm volatile("s_waitcnt vmcnt(%0)" ::"n"(LOADS) : "memory");
    } else if (T + 1 < NT) {
      asm volatile("s_waitcnt vmcnt(0)" ::: "memory");
    }
    __builtin_amdgcn_s_barrier();
    __builtin_amdgcn_sched_barrier(0);
  }

  // epilogue. C/D frag layout: col = idx, row = 4*g + j (round-1 verified)
  if (SCORE) {
    short* S = (short*)Cout;
#pragma unroll
    for (int mf = 0; mf < MF; ++mf) {
#pragma unroll
      for (int j = 0; j < 4; ++j) {
        const int row = row0 + wm * (BM / WM) + mf * 16 + g * 4 + j;
        float ss = 0.f;
#pragma unroll
        for (int nf = 0; nf < NF; ++nf) {
          const float v = acc[mf][nf][j];
          ss += v * v;
          S[(size_t)row * N + col0 + wn * (BN / WN) + nf * 16 + idx] = f2bf(v);
        }
        ss += __shfl_xor(ss, 1);
        ss += __shfl_xor(ss, 2);
        ss += __shfl_xor(ss, 4);
        ss += __shfl_xor(ss, 8);
        if (idx == 0) atomicAdd(&rowss[row], ss);
      }
    }
  } else {
    float* C = (float*)Cout;
#pragma unroll
    for (int mf = 0; mf < MF; ++mf)
#pragma unroll
      for (int j = 0; j < 4; ++j) {
        const int row = row0 + wm * (BM / WM) + mf * 16 + g * 4 + j;
#pragma unroll
        for (int nf = 0; nf < NF; ++nf)
          C[(size_t)row * N + col0 + wn * (BN / WN) + nf * 16 + idx] =
              acc[mf][nf][j];
      }
  }
}

// ---------------- normalize + exact GELU, in place on bf16 scores ----------------
__global__ void norm_gelu_kernel(short* __restrict__ S,
                                 const float* __restrict__ rowss, int total8) {
  int i = blockIdx.x * blockDim.x + threadIdx.x;
  if (i >= total8) return;
  size_t base = (size_t)i * 8;
  int row = (int)(base >> 12);               // / 4096 cols
  float scale = 64.0f * rsqrtf(rowss[row]);  // sqrt(N)/l2
  short8 v = *(short8*)(S + base);
  short8 o;
#pragma unroll
  for (int k = 0; k < 8; ++k) {
    float x = bf2f(v[k]) * scale;
    float gl = 0.5f * x * (1.0f + erff(x * 0.70710678118654752f));
    o[k] = f2bf(gl);
  }
  *(short8*)(S + base) = o;
}

extern "C" void kernel_launch(void* const* d_in, const int* in_sizes, int n_in,
                              void* d_out, int out_size, void* d_ws,
                              size_t ws_size, hipStream_t stream) {
  const float* X = (const float*)d_in[0];   // [8192,1024]
  const float* Kp = (const float*)d_in[1];  // [4096,1024]
  const float* Vp = (const float*)d_in[2];  // [4096,1024]
  float* out = (float*)d_out;               // [8192,1024] f32

  const int M = 8192, D1 = 1024, Nn = 4096, D2 = 1024;

  char* ws = (char*)d_ws;
  short* Xb = (short*)ws; ws += (size_t)M * D1 * 2;   // 16 MiB
  short* Kb = (short*)ws; ws += (size_t)Nn * D1 * 2;  // 8 MiB
  short* Vt = (short*)ws; ws += (size_t)D2 * Nn * 2;  // 8 MiB
  short* S  = (short*)ws; ws += (size_t)M * Nn * 2;   // 64 MiB
  float* rowss = (float*)ws;                          // 32 KiB
  (void)ws_size;

  hipMemsetAsync(rowss, 0, M * sizeof(float), stream);
  f32_to_bf16_kernel<<<(M * D1 / 8 + 255) / 256, 256, 0, stream>>>(X, Xb, M * D1 / 8);
  f32_to_bf16_kernel<<<(Nn * D1 / 8 + 255) / 256, 256, 0, stream>>>(Kp, Kb, Nn * D1 / 8);
  transpose_bf16_kernel<<<dim3(Nn / 64, D2 / 64), 256, 0, stream>>>(Vp, Vt, Nn, D2);

  // GEMM1: scores = Xb @ Kb^T  (M=8192, N=4096, K=1024), bf16 out + row sumsq
  gemm_pipe<256, 2, 4, true><<<dim3((M / 256) * (Nn / 256)), 512, 0, stream>>>(
      Xb, Kb, S, rowss, M, Nn, D1);

  norm_gelu_kernel<<<(M * Nn / 8 + 255) / 256, 256, 0, stream>>>(S, rowss, M * Nn / 8);

  // GEMM2: out = W @ Vt^T  (M=8192, N=1024, K=4096), f32 out
  gemm_pipe<128, 4, 2, false><<<dim3((M / 256) * (D2 / 128)), 512, 0, stream>>>(
      S, Vt, out, nullptr, M, D2, Nn);
}

// Round 3
// 203.656 us; speedup vs baseline: 1.2556x; 1.0682x over previous
//
#include <hip/hip_runtime.h>
#include <hip/hip_bf16.h>
#include <math.h>
#include <stdint.h>

typedef __attribute__((ext_vector_type(8))) short short8;
typedef __attribute__((ext_vector_type(4))) float f32x4;

__device__ inline short f2bf(float x) {
  union { float f; uint32_t u; } c; c.f = x;
  uint32_t r = (c.u + 0x7FFFu + ((c.u >> 16) & 1u)) >> 16;
  return (short)(uint16_t)r;
}
__device__ inline float bf2f(short s) {
  union { uint32_t u; float f; } c; c.u = ((uint32_t)(uint16_t)s) << 16;
  return c.f;
}

__device__ inline void gload16(const short* src, const char* ldsdst) {
  __builtin_amdgcn_global_load_lds(
      (const __attribute__((address_space(1))) void*)src,
      (__attribute__((address_space(3))) void*)ldsdst, 16, 0, 0);
}

#define BAR __builtin_amdgcn_s_barrier()
#define LGKM0                                          \
  do {                                                 \
    asm volatile("s_waitcnt lgkmcnt(0)" ::: "memory"); \
    __builtin_amdgcn_sched_barrier(0);                 \
  } while (0)
#define VMC(n) asm volatile("s_waitcnt vmcnt(" #n ")" ::: "memory")

// ---------------- prep: f32 -> bf16 ----------------
__global__ void f32_to_bf16_kernel(const float* __restrict__ in,
                                   short* __restrict__ out, int n8) {
  int i = blockIdx.x * blockDim.x + threadIdx.x;
  if (i >= n8) return;
  const float4* p = (const float4*)(in + (size_t)i * 8);
  float4 a = p[0], b = p[1];
  short8 o;
  o[0] = f2bf(a.x); o[1] = f2bf(a.y); o[2] = f2bf(a.z); o[3] = f2bf(a.w);
  o[4] = f2bf(b.x); o[5] = f2bf(b.y); o[6] = f2bf(b.z); o[7] = f2bf(b.w);
  *(short8*)(out + (size_t)i * 8) = o;
}

// ---------------- prep: V[4096,1024] f32 -> Vt[1024,4096] bf16 ----------------
__global__ void transpose_bf16_kernel(const float* __restrict__ V,
                                      short* __restrict__ Vt,
                                      int rows, int cols) {
  __shared__ float tile[64][65];
  int n0 = blockIdx.x * 64;
  int d0 = blockIdx.y * 64;
  int t = threadIdx.x;
#pragma unroll
  for (int r = 0; r < 16; ++r) {
    int idx = t + 256 * r;
    int rr = idx >> 6, cc = idx & 63;
    tile[rr][cc] = V[(size_t)(n0 + rr) * cols + d0 + cc];
  }
  __syncthreads();
#pragma unroll
  for (int r = 0; r < 16; ++r) {
    int idx = t + 256 * r;
    int dd = idx >> 6, nn = idx & 63;
    Vt[(size_t)(d0 + dd) * rows + n0 + nn] = f2bf(tile[nn][dd]);
  }
}

// ======== GEMM1: S[8192,4096](bf16) = Xb[8192,1024] x Kb[4096,1024]^T ========
// BM=BN=256, BK=64, 8 waves (2x4), 4 phases/tile, dbuf LDS 128 KiB.
__global__ __launch_bounds__(512, 2) void gemm1_kernel(
    const short* __restrict__ A, const short* __restrict__ B,
    short* __restrict__ S, float* __restrict__ rowss) {
  constexpr int K = 1024, N = 4096, NT = K / 64;
  __shared__ char lds[2 * 65536];  // per buf: A 32K @0, B 32K @32768
  const int t = threadIdx.x, lane = t & 63, w = t >> 6;
  const int wm = w >> 2, wn = w & 3;
  const int idx = lane & 15, g = lane >> 4;
  const int bid = blockIdx.x;
  const int id2 = (bid & 7) * 64 + (bid >> 3);  // 512 blocks, bijective
  const int row0 = (id2 >> 4) * 256, col0 = (id2 & 15) * 256;

  const int srow = t >> 3;                 // 0..63 within a round
  const int ksl = (t & 7) ^ (srow & 7);    // pre-swizzled 16B k-slot
  const short* gA = A + (size_t)(row0 + srow) * K + ksl * 8;
  const short* gB = B + (size_t)(col0 + srow) * K + ksl * 8;

  // one half-tile = 2 rounds x 8 KiB (64 rows x 128B)
  auto stageA = [&](int buf, int frow, int kt) {
#pragma unroll
    for (int r = 0; r < 2; ++r)
      gload16(gA + (size_t)(frow + r * 64) * K + kt,
              &lds[buf * 65536 + (frow + r * 64) * 128 + t * 16]);
  };
  auto stageB = [&](int buf, int frow, int kt) {
#pragma unroll
    for (int r = 0; r < 2; ++r)
      gload16(gB + (size_t)(frow + r * 64) * K + kt,
              &lds[buf * 65536 + 32768 + (frow + r * 64) * 128 + t * 16]);
  };

  const int xv = (idx & 7) << 4;
  short8 a[4][2], b[2][2][2];
  auto lda = [&](int buf, int mh) {
#pragma unroll
    for (int f = 0; f < 4; ++f)
#pragma unroll
      for (int ks = 0; ks < 2; ++ks) {
        int row = mh * 128 + wm * 64 + f * 16 + idx;
        int byte = row * 128 + ((ks * 64 + g * 16) ^ xv);
        a[f][ks] = *(const short8*)&lds[buf * 65536 + byte];
      }
  };
  auto ldb = [&](int buf, int nh) {
#pragma unroll
    for (int nf = 0; nf < 2; ++nf)
#pragma unroll
      for (int ks = 0; ks < 2; ++ks) {
        int col = nh * 128 + wn * 32 + nf * 16 + idx;
        int byte = col * 128 + ((ks * 64 + g * 16) ^ xv);
        b[nh][nf][ks] = *(const short8*)&lds[buf * 65536 + 32768 + byte];
      }
  };

  f32x4 acc[8][4] = {};
  auto MF = [&](int mh, int nh) {
    __builtin_amdgcn_s_setprio(1);
#pragma unroll
    for (int ks = 0; ks < 2; ++ks)
#pragma unroll
      for (int f = 0; f < 4; ++f)
#pragma unroll
        for (int n = 0; n < 2; ++n)
          acc[mh * 4 + f][nh * 2 + n] = __builtin_amdgcn_mfma_f32_16x16x32_bf16(
              a[f][ks], b[nh][n][ks], acc[mh * 4 + f][nh * 2 + n], 0, 0, 0);
    __builtin_amdgcn_s_setprio(0);
    __builtin_amdgcn_sched_barrier(0);
  };

  // prologue: tile 0 in stream order [Alo,Blo,Bhi,Ahi]; certify Alo,Blo
  stageA(0, 0, 0);
  stageB(0, 0, 0);
  stageB(0, 128, 0);
  stageA(0, 128, 0);
  VMC(4);
  BAR;

  for (int tb = 0; tb < NT; tb += 2) {
#pragma unroll
    for (int u = 0; u < 2; ++u) {
      const int T = tb + u, buf = u, nbuf = u ^ 1;
      const int kt1 = (T + 1) * 64;
      const bool more = (T + 1 < NT);
      // p1: quadrant (m0,n0)
      lda(buf, 0); ldb(buf, 0);
      if (more) stageA(nbuf, 0, kt1);  // Alo(t+1)
      BAR; LGKM0; MF(0, 0);
      if (more) { VMC(4); } else { VMC(2); }  // certify Bhi(t)
      BAR;
      // p2: quadrant (m0,n1)
      ldb(buf, 1);
      if (more) stageB(nbuf, 0, kt1);  // Blo(t+1)
      BAR; LGKM0; MF(0, 1);
      if (more) { VMC(4); } else { VMC(0); }  // certify Ahi(t)
      BAR;
      // p3: quadrant (m1,n1)
      lda(buf, 1);
      if (more) stageB(nbuf, 128, kt1);  // Bhi(t+1)
      BAR; LGKM0; MF(1, 1);
      BAR;
      // p4: quadrant (m1,n0) — no new reads (a from p3, b0 from p1)
      if (more) stageA(nbuf, 128, kt1);  // Ahi(t+1)
      BAR; MF(1, 0);
      if (more) VMC(4);  // certify Alo,Blo(t+1)
      BAR;
    }
  }

  // epilogue: C/D col=idx, row=4g+j within the 16x16 frag tile
#pragma unroll
  for (int mf = 0; mf < 8; ++mf) {
#pragma unroll
    for (int j = 0; j < 4; ++j) {
      const int row = row0 + wm * 64 + (mf & 3) * 16 + (mf >> 2) * 128 + g * 4 + j;
      float ss = 0.f;
#pragma unroll
      for (int nf = 0; nf < 4; ++nf) {
        const float v = acc[mf][nf][j];
        ss += v * v;
        const int col = col0 + wn * 32 + (nf & 1) * 16 + (nf >> 1) * 128 + idx;
        S[(size_t)row * N + col] = f2bf(v);
      }
      ss += __shfl_xor(ss, 1);
      ss += __shfl_xor(ss, 2);
      ss += __shfl_xor(ss, 4);
      ss += __shfl_xor(ss, 8);
      if (idx == 0) atomicAdd(&rowss[row], ss);
    }
  }
}

// ======== GEMM2: out[8192,1024](f32) = S[8192,4096] x Vt[1024,4096]^T ========
// BM=256, BN=128, BK=64, 8 waves (4x2), 2 phases/tile, dbuf LDS 96 KiB.
__global__ __launch_bounds__(512, 2) void gemm2_kernel(
    const short* __restrict__ A, const short* __restrict__ B,
    float* __restrict__ C) {
  constexpr int K = 4096, N = 1024, NT = K / 64;
  __shared__ char lds[2 * 49152];  // per buf: A 32K @0, B 16K @32768
  const int t = threadIdx.x, lane = t & 63, w = t >> 6;
  const int wm = w >> 1, wn = w & 1;
  const int idx = lane & 15, g = lane >> 4;
  const int bid = blockIdx.x;
  const int id2 = (bid & 7) * 32 + (bid >> 3);  // 256 blocks
  const int row0 = (id2 >> 3) * 256, col0 = (id2 & 7) * 128;

  const int srow = t >> 3;
  const int ksl = (t & 7) ^ (srow & 7);
  const short* gA = A + (size_t)(row0 + srow) * K + ksl * 8;
  const short* gB = B + (size_t)(col0 + srow) * K + ksl * 8;

  auto stageAr = [&](int buf, int fr, int kt) {  // one 8 KiB round
    gload16(gA + (size_t)(fr)*K + kt, &lds[buf * 49152 + fr * 128 + t * 16]);
  };
  auto stageB = [&](int buf, int kt) {  // both rounds (16 KiB)
#pragma unroll
    for (int r = 0; r < 2; ++r)
      gload16(gB + (size_t)(r * 64) * K + kt,
              &lds[buf * 49152 + 32768 + r * 8192 + t * 16]);
  };

  const int xv = (idx & 7) << 4;
  short8 a[2][2], b[4][2];
  auto lda = [&](int buf, int mh) {
#pragma unroll
    for (int f = 0; f < 2; ++f)
#pragma unroll
      for (int ks = 0; ks < 2; ++ks) {
        int row = mh * 128 + wm * 32 + f * 16 + idx;
        int byte = row * 128 + ((ks * 64 + g * 16) ^ xv);
        a[f][ks] = *(const short8*)&lds[buf * 49152 + byte];
      }
  };
  auto ldb = [&](int buf) {
#pragma unroll
    for (int nf = 0; nf < 4; ++nf)
#pragma unroll
      for (int ks = 0; ks < 2; ++ks) {
        int col = wn * 64 + nf * 16 + idx;
        int byte = col * 128 + ((ks * 64 + g * 16) ^ xv);
        b[nf][ks] = *(const short8*)&lds[buf * 49152 + 32768 + byte];
      }
  };

  f32x4 acc[4][4] = {};
  auto MF = [&](int mh) {
    __builtin_amdgcn_s_setprio(1);
#pragma unroll
    for (int ks = 0; ks < 2; ++ks)
#pragma unroll
      for (int f = 0; f < 2; ++f)
#pragma unroll
        for (int nf = 0; nf < 4; ++nf)
          acc[mh * 2 + f][nf] = __builtin_amdgcn_mfma_f32_16x16x32_bf16(
              a[f][ks], b[nf][ks], acc[mh * 2 + f][nf], 0, 0, 0);
    __builtin_amdgcn_s_setprio(0);
    __builtin_amdgcn_sched_barrier(0);
  };

  // prologue: stream [B, Alo(r0,r1), Ahi(r0,r1)](0); certify B+Alo
  stageB(0, 0);
  stageAr(0, 0, 0);
  stageAr(0, 64, 0);
  stageAr(0, 128, 0);
  stageAr(0, 192, 0);
  VMC(2);
  BAR;

  for (int tb = 0; tb < NT; tb += 2) {
#pragma unroll
    for (int u = 0; u < 2; ++u) {
      const int T = tb + u, buf = u, nbuf = u ^ 1;
      const int kt1 = (T + 1) * 64;
      const bool more = (T + 1 < NT);
      // p1: m-half 0 (uses all B)
      ldb(buf); lda(buf, 0);
      if (more) { stageB(nbuf, kt1); stageAr(nbuf, 0, kt1); }
      BAR; LGKM0; MF(0);
      if (more) { VMC(3); } else { VMC(0); }  // certify Ahi(t)
      BAR;
      // p2: m-half 1
      lda(buf, 1);
      if (more) { stageAr(nbuf, 64, kt1); stageAr(nbuf, 128, kt1); stageAr(nbuf, 192, kt1); }
      BAR; LGKM0; MF(1);
      if (more) VMC(2);  // certify B+Alo(t+1)
      BAR;
    }
  }

#pragma unroll
  for (int mf = 0; mf < 4; ++mf)
#pragma unroll
    for (int j = 0; j < 4; ++j) {
      const int row = row0 + wm * 32 + (mf & 1) * 16 + (mf >> 1) * 128 + g * 4 + j;
#pragma unroll
      for (int nf = 0; nf < 4; ++nf)
        C[(size_t)row * N + col0 + wn * 64 + nf * 16 + idx] = acc[mf][nf][j];
    }
}

// ---------------- normalize + exact GELU ----------------
__global__ void norm_gelu_kernel(short* __restrict__ S,
                                 const float* __restrict__ rowss, int total8) {
  int i = blockIdx.x * blockDim.x + threadIdx.x;
  if (i >= total8) return;
  size_t base = (size_t)i * 8;
  int row = (int)(base >> 12);
  float scale = 64.0f * rsqrtf(rowss[row]);
  short8 v = *(short8*)(S + base);
  short8 o;
#pragma unroll
  for (int k = 0; k < 8; ++k) {
    float x = bf2f(v[k]) * scale;
    float gl = 0.5f * x * (1.0f + erff(x * 0.70710678118654752f));
    o[k] = f2bf(gl);
  }
  *(short8*)(S + base) = o;
}

extern "C" void kernel_launch(void* const* d_in, const int* in_sizes, int n_in,
                              void* d_out, int out_size, void* d_ws,
                              size_t ws_size, hipStream_t stream) {
  const float* X = (const float*)d_in[0];
  const float* Kp = (const float*)d_in[1];
  const float* Vp = (const float*)d_in[2];
  float* out = (float*)d_out;

  const int M = 8192, D1 = 1024, Nn = 4096, D2 = 1024;

  char* ws = (char*)d_ws;
  short* Xb = (short*)ws; ws += (size_t)M * D1 * 2;
  short* Kb = (short*)ws; ws += (size_t)Nn * D1 * 2;
  short* Vt = (short*)ws; ws += (size_t)D2 * Nn * 2;
  short* S  = (short*)ws; ws += (size_t)M * Nn * 2;
  float* rowss = (float*)ws;
  (void)ws_size;

  hipMemsetAsync(rowss, 0, M * sizeof(float), stream);
  f32_to_bf16_kernel<<<(M * D1 / 8 + 255) / 256, 256, 0, stream>>>(X, Xb, M * D1 / 8);
  f32_to_bf16_kernel<<<(Nn * D1 / 8 + 255) / 256, 256, 0, stream>>>(Kp, Kb, Nn * D1 / 8);
  transpose_bf16_kernel<<<dim3(Nn / 64, D2 / 64), 256, 0, stream>>>(Vp, Vt, Nn, D2);

  gemm1_kernel<<<512, 512, 0, stream>>>(Xb, Kb, S, rowss);
  norm_gelu_kernel<<<(M * Nn / 8 + 255) / 256, 256, 0, stream>>>(S, rowss, M * Nn / 8);
  gemm2_kernel<<<256, 512, 0, stream>>>(S, Vt, out);
}

// Round 5
// 194.419 us; speedup vs baseline: 1.3153x; 1.0475x over previous
//
#include <hip/hip_runtime.h>
#include <hip/hip_bf16.h>
#include <math.h>
#include <stdint.h>

typedef __attribute__((ext_vector_type(8))) short short8;
typedef __attribute__((ext_vector_type(4))) float f32x4;

__device__ inline short f2bf(float x) {
  union { float f; uint32_t u; } c; c.f = x;
  uint32_t r = (c.u + 0x7FFFu + ((c.u >> 16) & 1u)) >> 16;
  return (short)(uint16_t)r;
}
__device__ inline float bf2f(short s) {
  union { uint32_t u; float f; } c; c.u = ((uint32_t)(uint16_t)s) << 16;
  return c.f;
}

__device__ inline void gload16(const short* src, const char* ldsdst) {
  __builtin_amdgcn_global_load_lds(
      (const __attribute__((address_space(1))) void*)src,
      (__attribute__((address_space(3))) void*)ldsdst, 16, 0, 0);
}

#define BAR __builtin_amdgcn_s_barrier()
#define VMC(n) asm volatile("s_waitcnt vmcnt(" #n ")" ::: "memory")

// ---------------- prep: f32 -> bf16 ----------------
__global__ void f32_to_bf16_kernel(const float* __restrict__ in,
                                   short* __restrict__ out, int n8) {
  int i = blockIdx.x * blockDim.x + threadIdx.x;
  if (i >= n8) return;
  const float4* p = (const float4*)(in + (size_t)i * 8);
  float4 a = p[0], b = p[1];
  short8 o;
  o[0] = f2bf(a.x); o[1] = f2bf(a.y); o[2] = f2bf(a.z); o[3] = f2bf(a.w);
  o[4] = f2bf(b.x); o[5] = f2bf(b.y); o[6] = f2bf(b.z); o[7] = f2bf(b.w);
  *(short8*)(out + (size_t)i * 8) = o;
}

// ---------------- prep: V[4096,1024] f32 -> Vt[1024,4096] bf16 ----------------
__global__ void transpose_bf16_kernel(const float* __restrict__ V,
                                      short* __restrict__ Vt,
                                      int rows, int cols) {
  __shared__ float tile[64][65];
  int n0 = blockIdx.x * 64;
  int d0 = blockIdx.y * 64;
  int t = threadIdx.x;
#pragma unroll
  for (int r = 0; r < 16; ++r) {
    int idx = t + 256 * r;
    int rr = idx >> 6, cc = idx & 63;
    tile[rr][cc] = V[(size_t)(n0 + rr) * cols + d0 + cc];
  }
  __syncthreads();
#pragma unroll
  for (int r = 0; r < 16; ++r) {
    int idx = t + 256 * r;
    int dd = idx >> 6, nn = idx & 63;
    Vt[(size_t)(d0 + dd) * rows + n0 + nn] = f2bf(tile[nn][dd]);
  }
}

// ======== GEMM1: S[8192,4096](bf16) = Xb[8192,1024] x Kb[4096,1024]^T ========
// BM=BN=256, BK=64, 8 waves (2x4), dbuf LDS 128 KiB.
// Sync: 2 barriers + 2 counted vmcnt per K-tile; every VMC immediately
// precedes a BAR (cross-wave certification invariant).
__global__ __launch_bounds__(512, 2) void gemm1_kernel(
    const short* __restrict__ A, const short* __restrict__ B,
    short* __restrict__ S, float* __restrict__ rowss) {
  constexpr int K = 1024, N = 4096, NT = K / 64;
  __shared__ char lds[2 * 65536];  // per buf: A 32K @0, B 32K @32768
  const int t = threadIdx.x, lane = t & 63, w = t >> 6;
  const int wm = w >> 2, wn = w & 3;
  const int idx = lane & 15, g = lane >> 4;
  const int bid = blockIdx.x;
  const int id2 = (bid & 7) * 64 + (bid >> 3);  // 512 blocks, bijective
  const int row0 = (id2 >> 4) * 256, col0 = (id2 & 15) * 256;

  const int srow = t >> 3;               // 0..63 within a round
  const int ksl = (t & 7) ^ (srow & 7);  // pre-swizzled 16B k-slot
  const short* gA = A + (size_t)(row0 + srow) * K + ksl * 8;
  const short* gB = B + (size_t)(col0 + srow) * K + ksl * 8;

  // one half-tile = 2 rounds x 8 KiB (64 rows x 128B)
  auto stageA = [&](int buf, int frow, int kt) {
#pragma unroll
    for (int r = 0; r < 2; ++r)
      gload16(gA + (size_t)(frow + r * 64) * K + kt,
              &lds[buf * 65536 + (frow + r * 64) * 128 + t * 16]);
  };
  auto stageB = [&](int buf, int frow, int kt) {
#pragma unroll
    for (int r = 0; r < 2; ++r)
      gload16(gB + (size_t)(frow + r * 64) * K + kt,
              &lds[buf * 65536 + 32768 + (frow + r * 64) * 128 + t * 16]);
  };

  const int xv = (idx & 7) << 4;
  short8 a[4][2], b[2][2][2];
  auto lda = [&](int buf, int mh) {
#pragma unroll
    for (int f = 0; f < 4; ++f)
#pragma unroll
      for (int ks = 0; ks < 2; ++ks) {
        int row = mh * 128 + wm * 64 + f * 16 + idx;
        int byte = row * 128 + ((ks * 64 + g * 16) ^ xv);
        a[f][ks] = *(const short8*)&lds[buf * 65536 + byte];
      }
  };
  auto ldb = [&](int buf, int nh) {
#pragma unroll
    for (int nf = 0; nf < 2; ++nf)
#pragma unroll
      for (int ks = 0; ks < 2; ++ks) {
        int col = nh * 128 + wn * 32 + nf * 16 + idx;
        int byte = col * 128 + ((ks * 64 + g * 16) ^ xv);
        b[nh][nf][ks] = *(const short8*)&lds[buf * 65536 + 32768 + byte];
      }
  };

  f32x4 acc[8][4] = {};
  auto MF = [&](int mh, int nh) {
    __builtin_amdgcn_s_setprio(1);
#pragma unroll
    for (int ks = 0; ks < 2; ++ks)
#pragma unroll
      for (int f = 0; f < 4; ++f)
#pragma unroll
        for (int n = 0; n < 2; ++n)
          acc[mh * 4 + f][nh * 2 + n] = __builtin_amdgcn_mfma_f32_16x16x32_bf16(
              a[f][ks], b[nh][n][ks], acc[mh * 4 + f][nh * 2 + n], 0, 0, 0);
    __builtin_amdgcn_s_setprio(0);
  };

  // prologue: stage tile 0 [Alo,Blo,Bhi,Ahi]; certify Alo,Blo,Bhi (6 of 8)
  stageA(0, 0, 0);
  stageB(0, 0, 0);
  stageB(0, 128, 0);
  stageA(0, 128, 0);
  VMC(2);
  BAR;

  for (int tb = 0; tb < NT; tb += 2) {
#pragma unroll
    for (int u = 0; u < 2; ++u) {
      const int T = tb + u, buf = u, nbuf = u ^ 1;
      const int kt1 = (T + 1) * 64;
      const bool more = (T + 1 < NT);
      // p1: quadrant (m0,n0) — Alo,Blo certified at boundary
      lda(buf, 0); ldb(buf, 0);
      if (more) stageA(nbuf, 0, kt1);  // Alo(t+1)
      MF(0, 0);
      // p2: quadrant (m0,n1) — Bhi certified at boundary
      ldb(buf, 1);
      if (more) stageB(nbuf, 0, kt1);  // Blo(t+1)
      MF(0, 1);
      // mid-tile: certify Ahi(t) across waves
      if (more) { VMC(4); } else { VMC(0); }
      BAR;
      // p3: quadrant (m1,n1)
      lda(buf, 1);
      if (more) stageB(nbuf, 128, kt1);  // Bhi(t+1)
      MF(1, 1);
      // p4: quadrant (m1,n0)
      if (more) stageA(nbuf, 128, kt1);  // Ahi(t+1)
      MF(1, 0);
      if (more) {
        VMC(2);  // certify Alo,Blo,Bhi(t+1)
        BAR;     // tile boundary
      }
    }
  }

  // epilogue: C/D col=idx, row=4g+j within the 16x16 frag tile
#pragma unroll
  for (int mf = 0; mf < 8; ++mf) {
#pragma unroll
    for (int j = 0; j < 4; ++j) {
      const int row = row0 + wm * 64 + (mf & 3) * 16 + (mf >> 2) * 128 + g * 4 + j;
      float ss = 0.f;
#pragma unroll
      for (int nf = 0; nf < 4; ++nf) {
        const float v = acc[mf][nf][j];
        ss += v * v;
        const int col = col0 + wn * 32 + (nf & 1) * 16 + (nf >> 1) * 128 + idx;
        S[(size_t)row * N + col] = f2bf(v);
      }
      ss += __shfl_xor(ss, 1);
      ss += __shfl_xor(ss, 2);
      ss += __shfl_xor(ss, 4);
      ss += __shfl_xor(ss, 8);
      if (idx == 0) atomicAdd(&rowss[row], ss);
    }
  }
}

// ======== GEMM2: out[8192,1024](f32) = S[8192,4096] x Vt[1024,4096]^T ========
// BM=256, BN=128, BK=64, 8 waves (4x2), dbuf LDS 96 KiB, 2 bar/tile.
__global__ __launch_bounds__(512, 2) void gemm2_kernel(
    const short* __restrict__ A, const short* __restrict__ B,
    float* __restrict__ C) {
  constexpr int K = 4096, N = 1024, NT = K / 64;
  __shared__ char lds[2 * 49152];  // per buf: A 32K @0, B 16K @32768
  const int t = threadIdx.x, lane = t & 63, w = t >> 6;
  const int wm = w >> 1, wn = w & 1;
  const int idx = lane & 15, g = lane >> 4;
  const int bid = blockIdx.x;
  const int id2 = (bid & 7) * 32 + (bid >> 3);  // 256 blocks
  const int row0 = (id2 >> 3) * 256, col0 = (id2 & 7) * 128;

  const int srow = t >> 3;
  const int ksl = (t & 7) ^ (srow & 7);
  const short* gA = A + (size_t)(row0 + srow) * K + ksl * 8;
  const short* gB = B + (size_t)(col0 + srow) * K + ksl * 8;

  auto stageAr = [&](int buf, int fr, int kt) {  // one 8 KiB round
    gload16(gA + (size_t)(fr)*K + kt, &lds[buf * 49152 + fr * 128 + t * 16]);
  };
  auto stageB = [&](int buf, int kt) {  // both rounds (16 KiB)
#pragma unroll
    for (int r = 0; r < 2; ++r)
      gload16(gB + (size_t)(r * 64) * K + kt,
              &lds[buf * 49152 + 32768 + r * 8192 + t * 16]);
  };

  const int xv = (idx & 7) << 4;
  short8 a[2][2], b[4][2];
  auto lda = [&](int buf, int mh) {
#pragma unroll
    for (int f = 0; f < 2; ++f)
#pragma unroll
      for (int ks = 0; ks < 2; ++ks) {
        int row = mh * 128 + wm * 32 + f * 16 + idx;
        int byte = row * 128 + ((ks * 64 + g * 16) ^ xv);
        a[f][ks] = *(const short8*)&lds[buf * 49152 + byte];
      }
  };
  auto ldb = [&](int buf) {
#pragma unroll
    for (int nf = 0; nf < 4; ++nf)
#pragma unroll
      for (int ks = 0; ks < 2; ++ks) {
        int col = wn * 64 + nf * 16 + idx;
        int byte = col * 128 + ((ks * 64 + g * 16) ^ xv);
        b[nf][ks] = *(const short8*)&lds[buf * 49152 + 32768 + byte];
      }
  };

  f32x4 acc[4][4] = {};
  auto MF = [&](int mh) {
    __builtin_amdgcn_s_setprio(1);
#pragma unroll
    for (int ks = 0; ks < 2; ++ks)
#pragma unroll
      for (int f = 0; f < 2; ++f)
#pragma unroll
        for (int nf = 0; nf < 4; ++nf)
          acc[mh * 2 + f][nf] = __builtin_amdgcn_mfma_f32_16x16x32_bf16(
              a[f][ks], b[nf][ks], acc[mh * 2 + f][nf], 0, 0, 0);
    __builtin_amdgcn_s_setprio(0);
  };

  // prologue: stage tile 0 [B,A0,A1,A2,A3]; certify B,A0,A1 (4 of 6)
  stageB(0, 0);
  stageAr(0, 0, 0);
  stageAr(0, 64, 0);
  stageAr(0, 128, 0);
  stageAr(0, 192, 0);
  VMC(2);
  BAR;

  for (int tb = 0; tb < NT; tb += 2) {
#pragma unroll
    for (int u = 0; u < 2; ++u) {
      const int T = tb + u, buf = u, nbuf = u ^ 1;
      const int kt1 = (T + 1) * 64;
      const bool more = (T + 1 < NT);
      // p1: m-half 0 (uses all B) — B,A0,A1 certified at boundary
      ldb(buf); lda(buf, 0);
      if (more) { stageB(nbuf, kt1); stageAr(nbuf, 0, kt1); stageAr(nbuf, 64, kt1); }
      MF(0);
      // mid-tile: certify A2,A3(t) across waves
      if (more) { VMC(4); } else { VMC(0); }
      BAR;
      // p2: m-half 1
      lda(buf, 1);
      if (more) { stageAr(nbuf, 128, kt1); stageAr(nbuf, 192, kt1); }
      MF(1);
      if (more) {
        VMC(2);  // certify B,A0,A1(t+1)
        BAR;
      }
    }
  }

#pragma unroll
  for (int mf = 0; mf < 4; ++mf)
#pragma unroll
    for (int j = 0; j < 4; ++j) {
      const int row = row0 + wm * 32 + (mf & 1) * 16 + (mf >> 1) * 128 + g * 4 + j;
#pragma unroll
      for (int nf = 0; nf < 4; ++nf)
        C[(size_t)row * N + col0 + wn * 64 + nf * 16 + idx] = acc[mf][nf][j];
    }
}

// ---------------- normalize + exact GELU ----------------
__global__ void norm_gelu_kernel(short* __restrict__ S,
                                 const float* __restrict__ rowss, int total8) {
  int i = blockIdx.x * blockDim.x + threadIdx.x;
  if (i >= total8) return;
  size_t base = (size_t)i * 8;
  int row = (int)(base >> 12);
  float scale = 64.0f * rsqrtf(rowss[row]);
  short8 v = *(short8*)(S + base);
  short8 o;
#pragma unroll
  for (int k = 0; k < 8; ++k) {
    float x = bf2f(v[k]) * scale;
    float gl = 0.5f * x * (1.0f + erff(x * 0.70710678118654752f));
    o[k] = f2bf(gl);
  }
  *(short8*)(S + base) = o;
}

extern "C" void kernel_launch(void* const* d_in, const int* in_sizes, int n_in,
                              void* d_out, int out_size, void* d_ws,
                              size_t ws_size, hipStream_t stream) {
  const float* X = (const float*)d_in[0];
  const float* Kp = (const float*)d_in[1];
  const float* Vp = (const float*)d_in[2];
  float* out = (float*)d_out;

  const int M = 8192, D1 = 1024, Nn = 4096, D2 = 1024;

  char* ws = (char*)d_ws;
  short* Xb = (short*)ws; ws += (size_t)M * D1 * 2;
  short* Kb = (short*)ws; ws += (size_t)Nn * D1 * 2;
  short* Vt = (short*)ws; ws += (size_t)D2 * Nn * 2;
  short* S  = (short*)ws; ws += (size_t)M * Nn * 2;
  float* rowss = (float*)ws;
  (void)ws_size;

  hipMemsetAsync(rowss, 0, M * sizeof(float), stream);
  f32_to_bf16_kernel<<<(M * D1 / 8 + 255) / 256, 256, 0, stream>>>(X, Xb, M * D1 / 8);
  f32_to_bf16_kernel<<<(Nn * D1 / 8 + 255) / 256, 256, 0, stream>>>(Kp, Kb, Nn * D1 / 8);
  transpose_bf16_kernel<<<dim3(Nn / 64, D2 / 64), 256, 0, stream>>>(Vp, Vt, Nn, D2);

  gemm1_kernel<<<512, 512, 0, stream>>>(Xb, Kb, S, rowss);
  norm_gelu_kernel<<<(M * Nn / 8 + 255) / 256, 256, 0, stream>>>(S, rowss, M * Nn / 8);
  gemm2_kernel<<<256, 512, 0, stream>>>(S, Vt, out);
}